// Round 8
// baseline (59.541 us; speedup 1.0000x reference)
//
#include <hip/hip_runtime.h>
#include <math.h>

constexpr int H_ = 180, W_ = 320, RF_ = 16, K_ = 20, T_ = 400;
constexpr int HW_ = H_ * W_;
constexpr int NWIN = T_ - K_ + 1;   // 381
constexpr int PW   = W_ + 2 * RF_;  // 352 (padded width used by rf_indices)
constexpr float ALPHA = 50.0f, BETA = 1.0f, GAMMA = 0.0f;
constexpr int NXCD = 8;
constexpr int T_PER_XCD = T_ / NXCD;   // 50 frames per XCD
constexpr int CH = 8;                  // frames per reduction chunk
constexpr int NCHUNK = (T_PER_XCD + CH - 1) / CH;   // 7 (last partial)

__device__ inline float wave_sum64(float v) {
#pragma unroll
    for (int off = 1; off < 64; off <<= 1)
        v += __shfl_xor(v, off, 64);
    return v;
}

// ---------------------------------------------------------------------------
// Kernel 0: factorize w (K x 256) into temporal[K] (x) spatial[256].
// w is an exact rank-1 outer product; LS-project onto the largest row.
// ---------------------------------------------------------------------------
__global__ void factorize_kernel(const float* __restrict__ w,
                                 float* __restrict__ spatial,   // 256
                                 float* __restrict__ temporal)  // K
{
    int l = threadIdx.x;  // 0..63
    float best = -1.0f;
    int k0 = 0;
    for (int k = 0; k < K_; ++k) {
        float s = 0.0f;
#pragma unroll
        for (int j = 0; j < 4; ++j) {
            float v = w[k * 256 + l + j * 64];
            s = fmaf(v, v, s);
        }
        s = wave_sum64(s);
        if (s > best) { best = s; k0 = k; }
    }
#pragma unroll
    for (int j = 0; j < 4; ++j)
        spatial[l + j * 64] = w[k0 * 256 + l + j * 64];
    float inv_s2 = 1.0f / best;
    for (int k = 0; k < K_; ++k) {
        float d = 0.0f;
#pragma unroll
        for (int j = 0; j < 4; ++j)
            d = fmaf(w[k * 256 + l + j * 64], w[k0 * 256 + l + j * 64], d);
        d = wave_sum64(d);
        if (l == 0) temporal[k] = d * inv_s2;
    }
}

// ---------------------------------------------------------------------------
// Kernel 1: y[n, t] = sum_p x_patch[t, n, p] * spatial[p]
//
// One wave per (neuron, 50-frame XCD range). Lane l = (window row lane>>2,
// column quad lane&3): one float4 load per lane = full 256-px RF of one
// frame per wave instruction. Clamped window origin + shifted/zeroed weights
// give exact zero-pad semantics with no per-iteration branching.
//
// ROUND-8 CHANGE: prefetch depth 2 (triple buffer A/B/C). 24 loads (3 chunks
// = 24 frames) are in flight before each REDSTORE, covering ~2 REDSTORE
// durations (~550-800 cy) of L3-miss latency instead of ~275 cy. Explicit
// 7-step unrolled schedule keeps all buffer indices compile-time (rule #20).
// ---------------------------------------------------------------------------
__global__ __launch_bounds__(256) void stage1_kernel(
    const float* __restrict__ x, const int* __restrict__ rf,
    const float* __restrict__ spatial, float* __restrict__ y,
    int N)
{
    int lane = threadIdx.x & 63;
    int wid  = threadIdx.x >> 6;

    int b   = blockIdx.x;
    int xcd = b & (NXCD - 1);
    int nch = b >> 3;

    int n = nch * 4 + wid;
    if (n >= N) return;
    int t0 = xcd * T_PER_XCD;

    int base = rf[n * 256];          // = v*PW + h (first padded index)
    int r0 = base / PW - RF_;        // window origin in frame (may be <0)
    int c0 = base % PW - RF_;
    int r0c = min(max(r0, 0), H_ - RF_);   // clamped origin (loads in-bounds)
    int c0c = min(max(c0, 0), W_ - RF_);

    int lr = lane >> 2;              // window row 0..15
    int q  = lane & 3;               // column quad 0..3
    int off = (r0c + lr) * W_ + c0c + q * 4;

    // weights matched to the CLAMPED window; outside true RF -> 0 (zero-pad)
    float wv[4];
    int rr = lr + (r0c - r0);
#pragma unroll
    for (int j = 0; j < 4; ++j) {
        int cc = q * 4 + j + (c0c - c0);
        bool ok = (rr >= 0) & (rr < RF_) & (cc >= 0) & (cc < RF_);
        wv[j] = ok ? spatial[rr * RF_ + cc] : 0.0f;
    }

    const float* xp = x + (size_t)t0 * HW_ + off;   // per-lane base pointer
    float* yp = y + (size_t)n * T_ + t0;

    int fr_out = ((lane & 1) << 2) | (lane & 2) | ((lane & 4) >> 2); // bitrev3

#define LOADCH(buf, cbase, clampf)                                            \
    do {                                                                      \
        _Pragma("unroll")                                                     \
        for (int j = 0; j < CH; ++j) {                                        \
            int f = (cbase) + j;                                              \
            if (clampf) f = f < T_PER_XCD ? f : T_PER_XCD - 1;                \
            buf[j] = *reinterpret_cast<const float4*>(xp + (size_t)f * HW_);  \
        }                                                                     \
    } while (0)

#define REDSTORE(buf, cbase)                                                  \
    do {                                                                      \
        float acc[CH];                                                        \
        _Pragma("unroll")                                                     \
        for (int j = 0; j < CH; ++j) {                                        \
            float a = buf[j].x * wv[0];                                       \
            a = fmaf(buf[j].y, wv[1], a);                                     \
            a = fmaf(buf[j].z, wv[2], a);                                     \
            acc[j] = fmaf(buf[j].w, wv[3], a);                                \
        }                                                                     \
        _Pragma("unroll")                                                     \
        for (int s = 0; s < 3; ++s) {                                         \
            const int m = 1 << s;                                             \
            const int half = CH >> (s + 1);                                   \
            bool hi = (lane & m) != 0;                                        \
            float nv[CH / 2];                                                 \
            _Pragma("unroll")                                                 \
            for (int j = 0; j < half; ++j) {                                  \
                float keep = hi ? acc[half + j] : acc[j];                     \
                float send = hi ? acc[j] : acc[half + j];                     \
                nv[j] = keep + __shfl_xor(send, m, 64);                       \
            }                                                                 \
            _Pragma("unroll")                                                 \
            for (int j = 0; j < half; ++j) acc[j] = nv[j];                    \
        }                                                                     \
        float r = acc[0];                                                     \
        r += __shfl_xor(r, 8, 64);                                            \
        r += __shfl_xor(r, 16, 64);                                           \
        r += __shfl_xor(r, 32, 64);                                           \
        if (lane < 8 && (cbase) + fr_out < T_PER_XCD)                         \
            yp[(cbase) + fr_out] = r;                                         \
    } while (0)

    // chunks: c0..c6 (c6 = frames 48..55, clamped; stores guarded).
    // Buffer map: c0,c3,c6 -> A ; c1,c4 -> B ; c2,c5 -> C.
    float4 bA[CH], bB[CH], bC[CH];
    LOADCH(bA, 0,  false);
    LOADCH(bB, 8,  false);
    LOADCH(bC, 16, false);

    REDSTORE(bA, 0);   LOADCH(bA, 24, false);
    REDSTORE(bB, 8);   LOADCH(bB, 32, false);
    REDSTORE(bC, 16);  LOADCH(bC, 40, false);
    REDSTORE(bA, 24);  LOADCH(bA, 48, true);
    REDSTORE(bB, 32);
    REDSTORE(bC, 40);
    REDSTORE(bA, 48);
#undef LOADCH
#undef REDSTORE
}

// ---------------------------------------------------------------------------
// Kernel 2: out[n, t0] = ALPHA * softplus(BETA * (sum_k y[n,t0+k]*temporal[k]
//                                                  - GAMMA))
// ---------------------------------------------------------------------------
__global__ void stage2_kernel(const float* __restrict__ y,
                              const float* __restrict__ temporal,
                              float* __restrict__ out, int N)
{
    __shared__ float tw[K_];
    if (threadIdx.x < K_) tw[threadIdx.x] = temporal[threadIdx.x];
    __syncthreads();

    int n  = blockIdx.x;
    int t0 = threadIdx.x;
    if (n >= N || t0 >= NWIN) return;

    const float* yn = y + (size_t)n * T_;
    float g = 0.0f;
#pragma unroll
    for (int k = 0; k < K_; ++k)
        g = fmaf(yn[t0 + k], tw[k], g);

    float z = BETA * (g - GAMMA);
    float sp = fmaxf(z, 0.0f) + log1pf(expf(-fabsf(z)));
    out[n * NWIN + t0] = ALPHA * sp;
}

// ---------------------------------------------------------------------------
extern "C" void kernel_launch(void* const* d_in, const int* in_sizes, int n_in,
                              void* d_out, int out_size, void* d_ws, size_t ws_size,
                              hipStream_t stream)
{
    const float* x  = (const float*)d_in[0];  // (T, H, W) f32
    const float* w  = (const float*)d_in[1];  // (K*RF*RF,) f32
    const int*   rf = (const int*)d_in[2];    // (N, 256) i32

    int N   = in_sizes[2] / (RF_ * RF_);
    int NCH = (N + 3) / 4;                    // 4 neurons (waves) per block

    float* spatial  = (float*)d_ws;           // 256
    float* temporal = spatial + 256;          // 20 (pad to 512)
    float* y        = spatial + 512;          // N * T

    factorize_kernel<<<1, 64, 0, stream>>>(w, spatial, temporal);
    stage1_kernel<<<NXCD * NCH, 256, 0, stream>>>(x, rf, spatial, y, N);
    stage2_kernel<<<N, 384, 0, stream>>>(y, temporal, (float*)d_out, N);
}

// Round 10
// 45.013 us; speedup vs baseline: 1.3228x; 1.3228x over previous
//
#include <hip/hip_runtime.h>
#include <math.h>

constexpr int H_ = 180, W_ = 320, RF_ = 16, K_ = 20, T_ = 400;
constexpr int HW_ = H_ * W_;
constexpr int NWIN = T_ - K_ + 1;   // 381
constexpr int PW   = W_ + 2 * RF_;  // 352 (padded width used by rf_indices)
constexpr float ALPHA = 50.0f, BETA = 1.0f, GAMMA = 0.0f;
constexpr int NXCD = 8;
constexpr int T_PER_XCD = T_ / NXCD;   // 50 frames per XCD
constexpr int CH = 8;                  // frames per reduction chunk

// ---------------------------------------------------------------------------
// Cross-lane primitives on the VALU pipe (DPP / permlane swap); DS only for
// the single xor-4 step (not expressible as row-DPP or permlane swap).
// ---------------------------------------------------------------------------
template <int CTRL>
__device__ inline float dpp_add(float v) {
    int s = __builtin_amdgcn_update_dpp(0, __float_as_int(v), CTRL, 0xF, 0xF, true);
    return v + __int_as_float(s);
}
// xor1 = quad_perm[1,0,3,2] = 0xB1 ; xor2 = quad_perm[2,3,0,1] = 0x4E ;
// xor8 (within 16-row) = row_ror:8 = 0x128
__device__ inline float swz_xor4_add(float v) {
    return v + __int_as_float(
        __builtin_amdgcn_ds_swizzle(__float_as_int(v), 0x101F));  // lane^4
}

#if __has_builtin(__builtin_amdgcn_permlane32_swap)
// result[l<32] = a[l]+a[l^32] ; result[l>=32] = b[l]+b[l^32]
__device__ inline float pl32_merge(float a, float b) {
    auto r = __builtin_amdgcn_permlane32_swap(
        __float_as_uint(a), __float_as_uint(b), false, false);
    return __uint_as_float(r[0]) + __uint_as_float(r[1]);
}
#else
__device__ inline float pl32_merge(float a, float b) {
    bool hi = (threadIdx.x & 32) != 0;
    float keep = hi ? b : a, send = hi ? a : b;
    return keep + __shfl_xor(send, 32, 64);
}
#endif

#if __has_builtin(__builtin_amdgcn_permlane16_swap)
// result[bit16=0] = a[l]+a[l^16] ; result[bit16=1] = b[l]+b[l^16]
__device__ inline float pl16_merge(float a, float b) {
    auto r = __builtin_amdgcn_permlane16_swap(
        __float_as_uint(a), __float_as_uint(b), false, false);
    return __uint_as_float(r[0]) + __uint_as_float(r[1]);
}
#else
__device__ inline float pl16_merge(float a, float b) {
    bool hi = (threadIdx.x & 16) != 0;
    float keep = hi ? b : a, send = hi ? a : b;
    return keep + __shfl_xor(send, 16, 64);
}
#endif

// full 64-lane allreduce, all-VALU except one ds_swizzle
__device__ inline float allred64(float v) {
    v = dpp_add<0xB1>(v);    // xor 1
    v = dpp_add<0x4E>(v);    // xor 2
    v = swz_xor4_add(v);     // xor 4
    v = dpp_add<0x128>(v);   // xor 8 (row_ror:8)
    v = pl16_merge(v, v);    // xor 16
    v = pl32_merge(v, v);    // xor 32
    return v;
}

// ---------------------------------------------------------------------------
// prep: factorize w (K x 256, exact rank-1) into spatial[256] + temporal[K].
// Parallel: wave w handles k = w, w+8, w+16 (DPP allreduce per row); argmax
// pivot row via LDS; LS-projection for temporal.
// ---------------------------------------------------------------------------
__global__ __launch_bounds__(512) void prep_kernel(
    const float* __restrict__ w,
    float* __restrict__ spatial, float* __restrict__ temporal)
{
    __shared__ float ss_l[32];
    int tid = threadIdx.x;
    int wv  = tid >> 6;   // 0..7
    int l   = tid & 63;

    for (int k = wv; k < K_; k += 8) {
        float s = 0.0f;
#pragma unroll
        for (int j = 0; j < 4; ++j) {
            float v = w[k * 256 + l + j * 64];
            s = fmaf(v, v, s);
        }
        s = allred64(s);
        if (l == 0) ss_l[k] = s;
    }
    __syncthreads();

    float best = -1.0f;
    int k0 = 0;
    for (int k = 0; k < K_; ++k) {
        float v = ss_l[k];
        if (v > best) { best = v; k0 = k; }
    }

    for (int k = wv; k < K_; k += 8) {
        float d = 0.0f;
#pragma unroll
        for (int j = 0; j < 4; ++j)
            d = fmaf(w[k * 256 + l + j * 64], w[k0 * 256 + l + j * 64], d);
        d = allred64(d);
        if (l == 0) temporal[k] = d / best;
    }
    if (tid < 256) spatial[tid] = w[k0 * 256 + tid];
}

// ---------------------------------------------------------------------------
// Stage 1: y[n, t] = sum_p x_patch[t, n, p] * spatial[p]
//
// One wave per (neuron, 50-frame XCD range); lane = (window row lane>>2,
// column quad lane&3) -> full 256-px RF in one float4 wave-load per frame.
// Clamped window + shifted/zeroed weights = exact zero-pad semantics.
//
// The 8-frame chunk reduction runs on the VALU pipe:
//   bit5: 4x permlane32_swap+add   bit4: 2x permlane16_swap+add
//   bit3: 2x row_ror:8 DPP self-add + 1 cndmask
//   bits 0,1: quad-perm DPP adds   bit2: one ds_swizzle
// -> 1 DS op per chunk instead of 10 serially-dependent ones.
// Lane 8j ends holding the full sum for frame tt+j.
// ---------------------------------------------------------------------------
__global__ __launch_bounds__(256) void stage1_kernel(
    const float* __restrict__ x, const int* __restrict__ rf,
    const float* __restrict__ spatial, float* __restrict__ y,
    int N)
{
    int lane = threadIdx.x & 63;
    int wid  = threadIdx.x >> 6;

    int b   = blockIdx.x;
    int xcd = b & (NXCD - 1);
    int nch = b >> 3;

    int n = nch * 4 + wid;
    if (n >= N) return;
    int t0 = xcd * T_PER_XCD;

    int base = rf[n * 256];
    int r0 = base / PW - RF_;
    int c0 = base % PW - RF_;
    int r0c = min(max(r0, 0), H_ - RF_);
    int c0c = min(max(c0, 0), W_ - RF_);

    int lr = lane >> 2;
    int q  = lane & 3;
    int off = (r0c + lr) * W_ + c0c + q * 4;

    float wv[4];
    int rr = lr + (r0c - r0);
#pragma unroll
    for (int j = 0; j < 4; ++j) {
        int cc = q * 4 + j + (c0c - c0);
        bool ok = (rr >= 0) & (rr < RF_) & (cc >= 0) & (cc < RF_);
        wv[j] = ok ? spatial[rr * RF_ + cc] : 0.0f;
    }

    const float* xp = x + (size_t)t0 * HW_ + off;
    float* yp = y + (size_t)n * T_ + t0;

    bool b8 = (lane & 8) != 0;

    // 6 full chunks of 8 frames (0..47)
    for (int tt = 0; tt < 48; tt += CH) {
        float4 buf[CH];
#pragma unroll
        for (int j = 0; j < CH; ++j)
            buf[j] = *reinterpret_cast<const float4*>(xp + (size_t)(tt + j) * HW_);

        float acc[CH];
#pragma unroll
        for (int j = 0; j < CH; ++j) {
            float a = buf[j].x * wv[0];
            a = fmaf(buf[j].y, wv[1], a);
            a = fmaf(buf[j].z, wv[2], a);
            acc[j] = fmaf(buf[j].w, wv[3], a);
        }

        // bit5 / bit4 merges (VALU permlane swaps)
        float m0 = pl32_merge(acc[0], acc[4]);
        float m1 = pl32_merge(acc[1], acc[5]);
        float m2 = pl32_merge(acc[2], acc[6]);
        float m3 = pl32_merge(acc[3], acc[7]);
        float n0 = pl16_merge(m0, m2);
        float n1 = pl16_merge(m1, m3);
        // bit3: ror8 self-add per register, then select by lane bit 3
        float c0v = dpp_add<0x128>(n0);
        float c1v = dpp_add<0x128>(n1);
        float C = b8 ? c1v : c0v;
        // bits 0,1,2 allreduce (same logical acc within each 8-lane group)
        C = dpp_add<0xB1>(C);
        C = dpp_add<0x4E>(C);
        C = swz_xor4_add(C);

        // lane 8j holds frame tt+j  (j = bit3 + 2*bit4 + 4*bit5)
        if ((lane & 7) == 0)
            yp[tt + (lane >> 3)] = C;
    }

    // tail frames 48, 49
#pragma unroll
    for (int f = 48; f < T_PER_XCD; ++f) {
        float4 v = *reinterpret_cast<const float4*>(xp + (size_t)f * HW_);
        float a = v.x * wv[0];
        a = fmaf(v.y, wv[1], a);
        a = fmaf(v.z, wv[2], a);
        a = fmaf(v.w, wv[3], a);
        a = allred64(a);
        if (lane == 0) yp[f] = a;
    }
}

// ---------------------------------------------------------------------------
// Stage 2: out[n, t0] = ALPHA * softplus(BETA * (sum_k y[n,t0+k]*temporal[k]
//                                                 - GAMMA))
// ---------------------------------------------------------------------------
__global__ void stage2_kernel(const float* __restrict__ y,
                              const float* __restrict__ temporal,
                              float* __restrict__ out, int N)
{
    __shared__ float tw[K_];
    if (threadIdx.x < K_) tw[threadIdx.x] = temporal[threadIdx.x];
    __syncthreads();

    int n  = blockIdx.x;
    int t0 = threadIdx.x;
    if (n >= N || t0 >= NWIN) return;

    const float* yn = y + (size_t)n * T_;
    float g = 0.0f;
#pragma unroll
    for (int k = 0; k < K_; ++k)
        g = fmaf(yn[t0 + k], tw[k], g);

    float z = BETA * (g - GAMMA);
    float sp = fmaxf(z, 0.0f) + log1pf(expf(-fabsf(z)));
    out[n * NWIN + t0] = ALPHA * sp;
}

// ---------------------------------------------------------------------------
extern "C" void kernel_launch(void* const* d_in, const int* in_sizes, int n_in,
                              void* d_out, int out_size, void* d_ws, size_t ws_size,
                              hipStream_t stream)
{
    const float* x  = (const float*)d_in[0];  // (T, H, W) f32
    const float* w  = (const float*)d_in[1];  // (K*RF*RF,) f32
    const int*   rf = (const int*)d_in[2];    // (N, 256) i32

    int N   = in_sizes[2] / (RF_ * RF_);
    int NCH = (N + 3) / 4;                    // 4 neurons (waves) per block

    float* spatial  = (float*)d_ws;           // 256
    float* temporal = spatial + 256;          // 20 (pad to 512)
    float* y        = spatial + 512;          // N * T

    prep_kernel<<<1, 512, 0, stream>>>(w, spatial, temporal);
    stage1_kernel<<<NXCD * NCH, 256, 0, stream>>>(x, rf, spatial, y, N);
    stage2_kernel<<<N, 384, 0, stream>>>(y, temporal, (float*)d_out, N);
}